// Round 1
// baseline (1057.285 us; speedup 1.0000x reference)
//
#include <hip/hip_runtime.h>
#include <hip/hip_bf16.h>

// Y[n,m,t] = mean_d (X1[n,t,d]-X2[m,t,d])^2
// = (||x1||^2 - 2*<x1,x2> + ||x2||^2)/D, cross term via bf16 MFMA.
// N=M=1024, T=64, D=128. Output [N,M,T] fp32 (t innermost!).
//
// Block = 512 threads = 8 waves; wave w handles t = tg*8+w and a full
// 64x64 (n,m) tile as 4x4 of 16x16x32-bf16 MFMAs (64 acc VGPRs/lane).
// No LDS: both operands are d-contiguous, matching the MFMA A/B fragment
// layout (lane holds 8 consecutive k elems) -> direct global->reg loads.
// Grid b = tg*256 + c: tg-pairs of the same (n,m) tile land on the same
// XCD (256 % 8 == 0) so the 32B half-line writes merge to full 64B lines
// in that XCD's L2 before eviction.

#define NN 1024
#define MM 1024
#define TT 64
#define DD 128

typedef __bf16 bf16x8 __attribute__((ext_vector_type(8)));
typedef float f32x4 __attribute__((ext_vector_type(4)));

__global__ __launch_bounds__(512, 4) void sim_kernel(
    const float* __restrict__ X1,
    const float* __restrict__ X2,
    float* __restrict__ Y)
{
    const int b  = blockIdx.x;
    const int tg = b >> 8;        // 0..7 t-group
    const int c  = b & 255;       // (n,m) tile id
    const int nt = c >> 4;
    const int mt = c & 15;
    const int n0 = nt << 6;
    const int m0 = mt << 6;

    const int wave = threadIdx.x >> 6;   // 0..7
    const int lane = threadIdx.x & 63;
    const int t = (tg << 3) + wave;
    const int q = lane >> 4;             // quad 0..3
    const int r = lane & 15;

    f32x4 acc[4][4] = {};
    float sqa[4] = {0.f, 0.f, 0.f, 0.f};
    float sqb[4] = {0.f, 0.f, 0.f, 0.f};

    // lane base element offset: row (n0|m0 + r), time t, d = q*8
    const int abase = ((n0 + r) * TT + t) * DD + (q << 3);
    const int bbase = ((m0 + r) * TT + t) * DD + (q << 3);

    #pragma unroll 1
    for (int kc = 0; kc < 4; ++kc) {
        const int koff = kc << 5;  // d chunk of 32
        bf16x8 af[4], bg[4];
        #pragma unroll
        for (int i = 0; i < 4; ++i) {
            const float* p = X1 + abase + i * (16 * TT * DD) + koff;
            f32x4 u0 = *(const f32x4*)p;
            f32x4 u1 = *(const f32x4*)(p + 4);
            sqa[i] += u0[0]*u0[0] + u0[1]*u0[1] + u0[2]*u0[2] + u0[3]*u0[3]
                    + u1[0]*u1[0] + u1[1]*u1[1] + u1[2]*u1[2] + u1[3]*u1[3];
            bf16x8 v;
            v[0] = (__bf16)u0[0]; v[1] = (__bf16)u0[1];
            v[2] = (__bf16)u0[2]; v[3] = (__bf16)u0[3];
            v[4] = (__bf16)u1[0]; v[5] = (__bf16)u1[1];
            v[6] = (__bf16)u1[2]; v[7] = (__bf16)u1[3];
            af[i] = v;
        }
        #pragma unroll
        for (int j = 0; j < 4; ++j) {
            const float* p = X2 + bbase + j * (16 * TT * DD) + koff;
            f32x4 u0 = *(const f32x4*)p;
            f32x4 u1 = *(const f32x4*)(p + 4);
            sqb[j] += u0[0]*u0[0] + u0[1]*u0[1] + u0[2]*u0[2] + u0[3]*u0[3]
                    + u1[0]*u1[0] + u1[1]*u1[1] + u1[2]*u1[2] + u1[3]*u1[3];
            bf16x8 v;
            v[0] = (__bf16)u0[0]; v[1] = (__bf16)u0[1];
            v[2] = (__bf16)u0[2]; v[3] = (__bf16)u0[3];
            v[4] = (__bf16)u1[0]; v[5] = (__bf16)u1[1];
            v[6] = (__bf16)u1[2]; v[7] = (__bf16)u1[3];
            bg[j] = v;
        }
        #pragma unroll
        for (int i = 0; i < 4; ++i)
            #pragma unroll
            for (int j = 0; j < 4; ++j)
                acc[i][j] = __builtin_amdgcn_mfma_f32_16x16x32_bf16(
                    af[i], bg[j], acc[i][j], 0, 0, 0);
    }

    // reduce row norms across quads: lanes {r, r+16, r+32, r+48} hold the
    // 4 disjoint d-quarters of row r
    float rowsq[4][4];
    #pragma unroll
    for (int i = 0; i < 4; ++i) {
        float v = sqa[i];
        v += __shfl_xor(v, 16);
        v += __shfl_xor(v, 32);
        // output row within 16-tile for acc reg rr is q*4+rr -> held by lane q*4+rr
        #pragma unroll
        for (int rr = 0; rr < 4; ++rr)
            rowsq[i][rr] = __shfl(v, (q << 2) + rr);
    }
    float colsq[4];
    #pragma unroll
    for (int j = 0; j < 4; ++j) {
        float v = sqb[j];
        v += __shfl_xor(v, 16);
        v += __shfl_xor(v, 32);
        colsq[j] = v;  // col within tile j is r == this lane's own row
    }

    // C/D layout (16x16x32): col = lane&15, row = (lane>>4)*4 + reg
    const float inv = 1.0f / 128.0f;
    #pragma unroll
    for (int i = 0; i < 4; ++i) {
        #pragma unroll
        for (int rr = 0; rr < 4; ++rr) {
            const int n = n0 + (i << 4) + (q << 2) + rr;
            float* yb = Y + (size_t)n * (MM * TT) + t;
            #pragma unroll
            for (int j = 0; j < 4; ++j) {
                const int m = m0 + (j << 4) + r;
                yb[m * TT] = (rowsq[i][rr] + colsq[j] - 2.0f * acc[i][j][rr]) * inv;
            }
        }
    }
}

extern "C" void kernel_launch(void* const* d_in, const int* in_sizes, int n_in,
                              void* d_out, int out_size, void* d_ws, size_t ws_size,
                              hipStream_t stream) {
    const float* X1 = (const float*)d_in[0];
    const float* X2 = (const float*)d_in[1];
    float* Y = (float*)d_out;
    sim_kernel<<<dim3(2048), dim3(512), 0, stream>>>(X1, X2, Y);
}

// Round 2
// 464.612 us; speedup vs baseline: 2.2756x; 2.2756x over previous
//
#include <hip/hip_runtime.h>
#include <hip/hip_bf16.h>

// Y[n,m,t] = mean_d (X1[n,t,d]-X2[m,t,d])^2
//          = (||x1||^2 - 2<x1,x2> + ||x2||^2)/D, cross via f16 MFMA.
// N=M=1024, T=64, D=128. Output [N,M,T] fp32, t innermost.
//
// Round-1 restructure: each 64B output line = 16 consecutive t of one (n,m),
// written entirely by ONE lane as 4 float4 stores -> no write amplification.
// Block = 1024 thr = 16 waves; tile 64(n) x 64(m) x 16(t). Wave = one 16x16
// (n,m) tile, all 16 t accumulated in regs (16 x f32x4 = 64 VGPR).
// Per t: stage A(64x128),B(64x128) fp32->f16 into LDS (norms in fp32 during
// staging), then each wave does 4 MFMAs (K=128) into acc[t].
// Grid: b = ((c>>3)*4 + tg)*8 + (c&7) -> the 4 t-groups of a (n,m) tile land
// on the same XCD close in time (128B-line merge insurance).

#define NN 1024
#define MM 1024
#define TT 64
#define DD 128

typedef _Float16 f16x8 __attribute__((ext_vector_type(8)));
typedef float f32x4 __attribute__((ext_vector_type(4)));

#define LDA 132   // f16 elems per LDS row (128 + 4 pad -> bank rotation)
#define LDN 17    // norm row stride in floats (conflict-free epilogue reads)

__global__ __launch_bounds__(1024) void sim_kernel(
    const float* __restrict__ X1, const float* __restrict__ X2,
    float* __restrict__ Y)
{
    __shared__ _Float16 As[64 * LDA];
    __shared__ _Float16 Bs[64 * LDA];
    __shared__ float an[64 * LDN];
    __shared__ float bn[64 * LDN];

    // decode swizzled block id
    const int b   = blockIdx.x;
    const int clo = b & 7;
    const int tg  = (b >> 3) & 3;
    const int chi = b >> 5;
    const int c   = (chi << 3) | clo;   // (n,m) tile id 0..255
    const int n0  = (c >> 4) << 6;
    const int m0  = (c & 15) << 6;
    const int t0  = tg << 4;

    const int tid  = threadIdx.x;
    const int lane = tid & 63;
    const int wave = tid >> 6;
    const int q = lane >> 4, r = lane & 15;
    const int wn = wave >> 2, wm = wave & 3;   // 4x4 wave grid over 64x64

    // staging: threads 0..511 -> A rows, 512..1023 -> B rows.
    // 8 threads per row, each covers 16 consecutive floats (64B).
    const bool isA = tid < 512;
    const int  srow = (tid >> 3) & 63;
    const int  scol = (tid & 7) << 4;
    const float*  Xsrc = isA ? X1 : X2;
    const int     grow = (isA ? n0 : m0) + srow;
    _Float16*     Ms = isA ? As : Bs;
    float*        Ns = isA ? an : bn;

    f32x4 acc[16];
    #pragma unroll
    for (int i = 0; i < 16; ++i) acc[i] = (f32x4){0.f, 0.f, 0.f, 0.f};

    // prologue: loads for tl = 0
    f32x4 u[4];
    {
        const float* p = Xsrc + ((size_t)grow * TT + t0) * DD + scol;
        u[0] = ((const f32x4*)p)[0]; u[1] = ((const f32x4*)p)[1];
        u[2] = ((const f32x4*)p)[2]; u[3] = ((const f32x4*)p)[3];
    }

    #pragma unroll
    for (int tl = 0; tl < 16; ++tl) {
        // fp32 sumsq + convert to f16 (in registers)
        float s = 0.f;
        #pragma unroll
        for (int j = 0; j < 4; ++j)
            s += u[j][0]*u[j][0] + u[j][1]*u[j][1] + u[j][2]*u[j][2] + u[j][3]*u[j][3];
        f16x8 h0, h1;
        #pragma unroll
        for (int e = 0; e < 4; ++e) { h0[e] = (_Float16)u[0][e]; h0[e+4] = (_Float16)u[1][e]; }
        #pragma unroll
        for (int e = 0; e < 4; ++e) { h1[e] = (_Float16)u[2][e]; h1[e+4] = (_Float16)u[3][e]; }
        s += __shfl_xor(s, 1); s += __shfl_xor(s, 2); s += __shfl_xor(s, 4);

        __syncthreads();                       // prev iter's frag reads done
        *(f16x8*)&Ms[srow * LDA + scol]     = h0;
        *(f16x8*)&Ms[srow * LDA + scol + 8] = h1;
        if ((tid & 7) == 0) Ns[srow * LDN + tl] = s;
        __syncthreads();                       // staging visible

        // prefetch next t (latency hidden behind MFMA phase)
        if (tl < 15) {
            const float* p = Xsrc + ((size_t)grow * TT + t0 + tl + 1) * DD + scol;
            u[0] = ((const f32x4*)p)[0]; u[1] = ((const f32x4*)p)[1];
            u[2] = ((const f32x4*)p)[2]; u[3] = ((const f32x4*)p)[3];
        }

        // fragments + MFMA: wave's 16x16 tile, K = 128 in 4 chunks
        #pragma unroll
        for (int kc = 0; kc < 4; ++kc) {
            f16x8 af = *(const f16x8*)&As[(wn*16 + r) * LDA + kc*32 + q*8];
            f16x8 bf = *(const f16x8*)&Bs[(wm*16 + r) * LDA + kc*32 + q*8];
            acc[tl] = __builtin_amdgcn_mfma_f32_16x16x32_f16(af, bf, acc[tl], 0, 0, 0);
        }
    }

    // epilogue: C/D layout (16x16): col(m)=lane&15, row(n)=(lane>>4)*4+reg
    float bnv[16];
    {
        const float* pb = &bn[(wm*16 + r) * LDN];
        #pragma unroll
        for (int e = 0; e < 16; ++e) bnv[e] = pb[e];
    }
    const float inv = 1.0f / 128.0f;
    #pragma unroll
    for (int rr = 0; rr < 4; ++rr) {
        const float* pa = &an[(wn*16 + q*4 + rr) * LDN];
        float anv[16];
        #pragma unroll
        for (int e = 0; e < 16; ++e) anv[e] = pa[e];
        const size_t n = (size_t)(n0 + wn*16 + q*4 + rr);
        const size_t m = (size_t)(m0 + wm*16 + r);
        float* yb = Y + (n * MM + m) * TT + t0;
        #pragma unroll
        for (int tq = 0; tq < 4; ++tq) {
            f32x4 o;
            #pragma unroll
            for (int e = 0; e < 4; ++e) {
                const int tl = tq*4 + e;
                o[e] = (anv[tl] + bnv[tl] - 2.0f * acc[tl][rr]) * inv;
            }
            ((f32x4*)yb)[tq] = o;   // 4 back-to-back 16B -> one full 64B line
        }
    }
}

extern "C" void kernel_launch(void* const* d_in, const int* in_sizes, int n_in,
                              void* d_out, int out_size, void* d_ws, size_t ws_size,
                              hipStream_t stream) {
    const float* X1 = (const float*)d_in[0];
    const float* X2 = (const float*)d_in[1];
    float* Y = (float*)d_out;
    sim_kernel<<<dim3(1024), dim3(1024), 0, stream>>>(X1, X2, Y);
}